// Round 13
// baseline (241.790 us; speedup 1.0000x reference)
//
#include <hip/hip_runtime.h>
#include <math.h>

// Problem: B=8, L=1024, C=768, nH=12, hd=64, qkv dim 2304. fp32 in, fp32 out.
#define NB 8
#define SL 1024
#define CD 768
#define NHH 12
#define HD 64
#define QKVD 2304

typedef __attribute__((ext_vector_type(8))) __bf16 bf16x8;
typedef __attribute__((ext_vector_type(8))) unsigned short u16x8;
typedef __attribute__((ext_vector_type(4))) float f32x4;
typedef __attribute__((ext_vector_type(16))) float f32x16;
typedef __attribute__((ext_vector_type(4))) unsigned int u32x4;
#define MFMA16(a, b, c) __builtin_amdgcn_mfma_f32_16x16x32_bf16(a, b, c, 0, 0, 0)
#define MFMA32(a, b, c) __builtin_amdgcn_mfma_f32_32x32x16_bf16(a, b, c, 0, 0, 0)

__host__ __device__ __forceinline__ float bf2f(unsigned short u) {
  union { unsigned int i; float f; } v; v.i = ((unsigned int)u) << 16; return v.f;
}
__host__ __device__ __forceinline__ unsigned short f2bf(float f) {
  union { float ff; unsigned int i; } v; v.ff = f;
  unsigned int x = v.i;
  x += 0x7FFFu + ((x >> 16) & 1u);  // RNE
  return (unsigned short)(x >> 16);
}
// pack two floats to bf16 pair (hw cvt, RNE) -> u32 (lo = first)
__device__ __forceinline__ unsigned int pkbf(float a, float b) {
  unsigned short ua = __builtin_bit_cast(unsigned short, (__bf16)a);
  unsigned short ub = __builtin_bit_cast(unsigned short, (__bf16)b);
  return ((unsigned int)ub << 16) | ua;
}

// async global->LDS, 16B per lane. LDS dest must be linear in lane order.
__device__ __forceinline__ void gload_lds16(const void* g, void* l) {
  __builtin_amdgcn_global_load_lds(
      (const __attribute__((address_space(1))) unsigned int*)g,
      (__attribute__((address_space(3))) unsigned int*)l, 16, 0, 0);
}

// Fused prep: 3x fp32->bf16 convert + RoPE cos/sin table, ONE launch.
#define PN0 (NB * SL * CD / 4)   // x float4s
#define PN1 (QKVD * CD / 4)      // w_qkv
#define PN2 (CD * CD / 4)        // w_out
#define PN3 (SL * 32)            // rope table entries
__global__ __launch_bounds__(256) void prep_kernel(
    const float4* __restrict__ x, const float4* __restrict__ wq,
    const float4* __restrict__ wo, ushort4* __restrict__ xb,
    ushort4* __restrict__ wqb, ushort4* __restrict__ wob,
    float2* __restrict__ rt)
{
  int i = blockIdx.x * 256 + threadIdx.x;
  if (i < PN0 + PN1 + PN2) {
    const float4* src; ushort4* dst; int k;
    if (i < PN0) { src = x; dst = xb; k = i; }
    else if (i < PN0 + PN1) { src = wq; dst = wqb; k = i - PN0; }
    else { src = wo; dst = wob; k = i - PN0 - PN1; }
    float4 v = src[k];
    ushort4 o;
    o.x = f2bf(v.x); o.y = f2bf(v.y); o.z = f2bf(v.z); o.w = f2bf(v.w);
    dst[k] = o;
  } else {
    int k = i - PN0 - PN1 - PN2;  // < PN3 by grid sizing
    int l = k >> 5, j = k & 31;
    float ang = (float)l * exp2f((float)j * (-13.287712379549449f / 32.0f));
    float sn, cs;
    sincosf(ang, &sn, &cs);
    rt[k] = make_float2(cs, sn);
  }
}

// C[M,N] = A[M,K] @ B[N,K]^T, A,B bf16.
// MODE 0: bf16 out. MODE 1: fp32 out. MODE 2: bf16 out with fused
// RMSNorm(hd=64)+RoPE (table-driven) on q/k head-columns.
// WR: wave-row multiplier. Tile = (128*WR) x 128, 4 waves in 2x2; each wave
// outputs (64*WR) x 64. WR=2 halves per-FLOP LDS-read traffic (12 fragment
// reads feed 32 MFMAs vs 8 for 16) — r12 arithmetic: 128^2 structure is
// LDS-read-BW-bound at 4.5 blocks/CU.
// 2-phase double-buffered gload_lds staging + 16B-chunk src-swizzle
// g(row)=(row>>1)&3 (invariant under +64-row call offsets and wm∈{0,64,128})
// + XCD block swizzle. s_setprio pair is LOAD-BEARING (r8-r11: removing it
// correlated with 1.7-1.9e-02 miscompares; r7/r12 with it pass) — DO NOT
// remove or restructure sync.
template <int MODE, int WR>
__global__ __launch_bounds__(256) void gemm_mfma(
    const unsigned short* __restrict__ A, const unsigned short* __restrict__ B,
    void* __restrict__ Cv, int M, int N, int K,
    const float* __restrict__ qg, const float* __restrict__ kg,
    const float2* __restrict__ rt)
{
  __shared__ alignas(16) unsigned short AsL[2][128 * WR * 32];
  __shared__ alignas(16) unsigned short BsL[2][128 * 32];
  // XCD swizzle (bijective: nwg % 8 == 0 for both gemm grids)
  const int bid = (int)(blockIdx.x + gridDim.x * blockIdx.y);
  const int cpx = (int)(gridDim.x * gridDim.y) >> 3;
  const int nb = (bid & 7) * cpx + (bid >> 3);
  const int bx = nb % (int)gridDim.x, by = nb / (int)gridDim.x;
  const int m0 = by * (128 * WR), n0 = bx * 128;
  const int t = threadIdx.x;
  const int wave = t >> 6, lane = t & 63;
  const int wm = (wave >> 1) * (64 * WR), wn = (wave & 1) * 64;
  const int lm = lane & 15, quad = lane >> 4;
  const int rq = (quad ^ ((lm >> 1) & 3)) * 8;  // swizzled read chunk offset
  f32x4 acc[4 * WR][4];
#pragma unroll
  for (int i = 0; i < 4 * WR; ++i)
#pragma unroll
    for (int j = 0; j < 4; ++j)
#pragma unroll
      for (int r = 0; r < 4; ++r) acc[i][j][r] = 0.f;

  // staging: thread t covers row sr (+64 per call), 16B chunk kc4;
  // source pre-swizzled: LDS[r][c] = G[r][c ^ ((r>>1)&3)].
  const int sr = t >> 2, kc4 = t & 3;
  const int scs = (kc4 ^ ((sr >> 1) & 3)) * 8;
  const unsigned short* ag = A + (size_t)(m0 + sr) * K + scs;
  const unsigned short* bg = B + (size_t)(n0 + sr) * K + scs;
#define STAGE_G(K0, BUF)                                                    \
  {                                                                         \
    _Pragma("unroll")                                                       \
    for (int c = 0; c < 2 * WR; ++c)                                        \
      gload_lds16(ag + (size_t)(64 * c) * K + (K0),                         \
                  &AsL[BUF][c * 2048 + t * 8]);                             \
    gload_lds16(bg + (K0), &BsL[BUF][t * 8]);                               \
    gload_lds16(bg + (size_t)64 * K + (K0), &BsL[BUF][2048 + t * 8]);       \
  }

  STAGE_G(0, 0);
  __syncthreads();
  int cur = 0;
  for (int k0 = 0; k0 < K; k0 += 32) {
    if (k0 + 32 < K) STAGE_G(k0 + 32, cur ^ 1);  // issue next (hides latency)
    bf16x8 af[4 * WR], bfr[4];
#pragma unroll
    for (int i = 0; i < 4 * WR; ++i)
      af[i] = *(const bf16x8*)&AsL[cur][(wm + i * 16 + lm) * 32 + rq];
#pragma unroll
    for (int j = 0; j < 4; ++j)
      bfr[j] = *(const bf16x8*)&BsL[cur][(wn + j * 16 + lm) * 32 + rq];
    __builtin_amdgcn_s_setprio(1);
#pragma unroll
    for (int i = 0; i < 4 * WR; ++i)
#pragma unroll
      for (int j = 0; j < 4; ++j)
        acc[i][j] = MFMA16(af[i], bfr[j], acc[i][j]);
    __builtin_amdgcn_s_setprio(0);
    __syncthreads();  // drains vmcnt (next-tile loads had MFMA time to land)
    cur ^= 1;
  }
#undef STAGE_G

  // ---- fused RMSNorm + RoPE epilogue (MODE 2, q/k planes only) ----
  // Wave covers cols [n0+wn, n0+wn+64) = exactly one head (hd=64; 128-aligned
  // tiles never straddle the s-plane boundaries at col 768/1536).
  if (MODE == 2 && (n0 + wn) < 2 * CD) {
    const float* gam = ((n0 + wn) >= CD) ? kg : qg;
    float g4[4];
#pragma unroll
    for (int j = 0; j < 4; ++j) g4[j] = gam[j * 16 + lm];
    unsigned short* Cs = (unsigned short*)Cv;
#pragma unroll
    for (int i = 0; i < 4 * WR; ++i) {
      const int row = m0 + wm + i * 16 + quad * 4;
#pragma unroll
      for (int r = 0; r < 4; ++r) {
        float v0 = acc[i][0][r], v1 = acc[i][1][r];
        float v2 = acc[i][2][r], v3 = acc[i][3][r];
        float ssq = v0 * v0 + v1 * v1 + v2 * v2 + v3 * v3;
#pragma unroll
        for (int off = 8; off; off >>= 1) ssq += __shfl_xor(ssq, off);
        const float sc2 = rsqrtf(ssq * (1.0f / 64.0f) + 1e-6f);
        v0 *= sc2 * g4[0]; v1 *= sc2 * g4[1];
        v2 *= sc2 * g4[2]; v3 *= sc2 * g4[3];
        const int l = (row + r) & (SL - 1);
        const float2 t0 = rt[l * 32 + lm];        // {cos,sin} dd=lm
        const float2 t1 = rt[l * 32 + 16 + lm];   // {cos,sin} dd=16+lm
        const size_t base = (size_t)(row + r) * N + n0 + wn + lm;
        Cs[base +  0] = f2bf(v0 * t0.x - v2 * t0.y);   // dd = lm
        Cs[base + 16] = f2bf(v1 * t1.x - v3 * t1.y);   // dd = 16+lm
        Cs[base + 32] = f2bf(v0 * t0.y + v2 * t0.x);   // dd = 32+lm
        Cs[base + 48] = f2bf(v1 * t1.y + v3 * t1.x);   // dd = 48+lm
      }
    }
    return;
  }

#pragma unroll
  for (int i = 0; i < 4 * WR; ++i) {
    const int row = m0 + wm + i * 16 + quad * 4;
#pragma unroll
    for (int r = 0; r < 4; ++r) {
      const size_t base = (size_t)(row + r) * N + n0 + wn + lm;
#pragma unroll
      for (int j = 0; j < 4; ++j) {
        if (MODE == 1) ((float*)Cv)[base + j * 16] = acc[i][j][r];
        else ((unsigned short*)Cv)[base + j * 16] = f2bf(acc[i][j][r]);
      }
    }
  }
}

// MFMA flash attention, v7 (byte-identical to r12's passing kernel):
// swapped-operand 32x32, in-register log2 softmax with defer-max, K via
// global_load_lds w16 (src-swizzled linear LDS), K/V double-buffered, one
// barrier/iter, XCD swizzle. setprio pair load-bearing (see gemm note).
__global__ __launch_bounds__(256) void attn_mfma(
    const unsigned short* __restrict__ qkv, unsigned short* __restrict__ ctx)
{
  __shared__ alignas(16) unsigned short KsL[2][64 * 64];  // linear, src-swizzled
  __shared__ alignas(16) unsigned short Vt[2][64][76];    // [d][key], stride 152B
  // XCD swizzle: grid (8,12,8) x-major linear; 768 = 8 XCD * 96.
  const int bid = (int)(blockIdx.x + 8 * (blockIdx.y + 12 * blockIdx.z));
  const int nb = (bid & 7) * 96 + (bid >> 3);  // bijective
  const int qt = nb & 7;
  const int h = (nb >> 3) % 12;
  const int b = nb / 96;
  const int t = threadIdx.x, wave = t >> 6, lane = t & 63;
  const int q_l = lane & 31, hi = lane >> 5;
  const int wq = wave * 32;                      // wave's q offset in 128-tile
  const int vkey = t & 63, vds = (t >> 6) * 16;  // V staging assignment
  const int kr = t >> 3, kc = t & 7;             // K staging: row, 16B chunk
  const float SCALE = 0.125f * 1.44269504088896340736f;  // 1/sqrt(64) * log2(e)

  const unsigned short* base_k = qkv + (size_t)b * SL * QKVD + (NHH * HD) + h * HD;
  const unsigned short* base_v = qkv + (size_t)b * SL * QKVD + 2 * (NHH * HD) + h * HD;

  // Q fragments (B-operand): Q[q = qt*128+wq+q_l][d = ds*16 + hi*8 + e]
  bf16x8 qf[4];
  {
    const unsigned short* qp =
        qkv + (((size_t)(b * SL + qt * 128 + wq + q_l) * 3 + 0) * NHH + h) * HD + hi * 8;
#pragma unroll
    for (int ds = 0; ds < 4; ++ds) qf[ds] = *(const bf16x8*)(qp + ds * 16);
  }
  f32x16 o0, o1;  // O^T[d = dt*32 + crow(r,hi)][q = q_l]
#pragma unroll
  for (int r = 0; r < 16; ++r) { o0[r] = 0.f; o1[r] = 0.f; }
  float m_i = -INFINITY, l_i = 0.f;  // log2-scaled units

  const int ksw = (kc ^ (kr & 7)) * 8;  // swizzled chunk, ushort offset
#define STAGE_K(KT, BUF)                                                      \
  {                                                                           \
    const unsigned short* k0p = base_k + (size_t)((KT)*64 + kr) * QKVD + ksw; \
    gload_lds16(k0p, &KsL[BUF][t * 8]);                                       \
    const unsigned short* k1p =                                               \
        base_k + (size_t)((KT)*64 + 32 + kr) * QKVD + ksw;                    \
    gload_lds16(k1p, &KsL[BUF][2048 + t * 8]);                                \
  }

  // prologue: stage tile 0 into buf 0
  STAGE_K(0, 0);
  {
    const unsigned short* vp = base_v + (size_t)vkey * QKVD + vds;
    u16x8 v0 = *(const u16x8*)(vp);
    u16x8 v1 = *(const u16x8*)(vp + 8);
#pragma unroll
    for (int e = 0; e < 8; ++e) {
      Vt[0][vds + e][vkey] = v0[e];
      Vt[0][vds + 8 + e][vkey] = v1[e];
    }
  }
  __syncthreads();

  for (int kt = 0; kt < 16; ++kt) {
    const int cur = kt & 1, nxt = cur ^ 1;
    const int ktn = (kt + 1) & 15;  // last iter re-stages tile 0 (unused)
    // ---- issue next tile's staging first (latency hides under compute) ----
    STAGE_K(ktn, nxt);
    const unsigned short* vp = base_v + (size_t)(ktn * 64 + vkey) * QKVD + vds;
    u16x8 v0n = *(const u16x8*)(vp);
    u16x8 v1n = *(const u16x8*)(vp + 8);
    // ---- S^T = K Q^T : st0 = keys 0-31, st1 = keys 32-63 ----
    const unsigned short* Kb = KsL[cur];
    f32x16 st0, st1;
#pragma unroll
    for (int r = 0; r < 16; ++r) { st0[r] = 0.f; st1[r] = 0.f; }
    __builtin_amdgcn_s_setprio(1);
#pragma unroll
    for (int ds = 0; ds < 4; ++ds) {
      const int c = 2 * ds + hi;  // 16B chunk covering d = ds*16 + hi*8
      bf16x8 k0 = *(const bf16x8*)&Kb[q_l * 64 + ((c ^ (q_l & 7)) * 8)];
      bf16x8 k1 = *(const bf16x8*)&Kb[(32 + q_l) * 64 + ((c ^ (q_l & 7)) * 8)];
      st0 = MFMA32(k0, qf[ds], st0);
      st1 = MFMA32(k1, qf[ds], st1);
    }
    __builtin_amdgcn_s_setprio(0);
    // ---- online softmax, log2 domain, defer-max ----
    float t0 = fmaxf(st0[0], st1[0]), t1 = fmaxf(st0[1], st1[1]);
    float t2 = fmaxf(st0[2], st1[2]), t3 = fmaxf(st0[3], st1[3]);
#pragma unroll
    for (int r = 4; r < 16; r += 4) {
      t0 = fmaxf(t0, fmaxf(st0[r + 0], st1[r + 0]));
      t1 = fmaxf(t1, fmaxf(st0[r + 1], st1[r + 1]));
      t2 = fmaxf(t2, fmaxf(st0[r + 2], st1[r + 2]));
      t3 = fmaxf(t3, fmaxf(st0[r + 3], st1[r + 3]));
    }
    float tm = fmaxf(fmaxf(t0, t1), fmaxf(t2, t3)) * SCALE;
    tm = fmaxf(tm, __shfl_xor(tm, 32));  // full 64-key max for this q
    if (!__all(tm - m_i <= 8.0f)) {      // rescale only on real max growth
      const float mn = fmaxf(m_i, tm);
      const float al = __builtin_amdgcn_exp2f(m_i - mn);
      m_i = mn;
      l_i *= al;
#pragma unroll
      for (int r = 0; r < 16; ++r) { o0[r] *= al; o1[r] *= al; }
    }
    float rs = 0.f;
#pragma unroll
    for (int r = 0; r < 16; ++r) {
      st0[r] = __builtin_amdgcn_exp2f(fmaf(st0[r], SCALE, -m_i));
      st1[r] = __builtin_amdgcn_exp2f(fmaf(st1[r], SCALE, -m_i));
      rs += st0[r] + st1[r];
    }
    rs += __shfl_xor(rs, 32);
    l_i += rs;
    // ---- P exchange + PV: per k-slot, build A-frag and MFMA immediately ----
#define PV_KS(KS, PVEC, RL)                                              \
    {                                                                    \
      unsigned int a0 = pkbf(PVEC[RL + 0], PVEC[RL + 1]);                \
      unsigned int a1 = pkbf(PVEC[RL + 2], PVEC[RL + 3]);                \
      unsigned int b0 = pkbf(PVEC[RL + 4], PVEC[RL + 5]);                \
      unsigned int b1 = pkbf(PVEC[RL + 6], PVEC[RL + 7]);                \
      unsigned int s0 = hi ? a0 : b0, s1 = hi ? a1 : b1;                 \
      unsigned int r0 = __shfl_xor(s0, 32), r1 = __shfl_xor(s1, 32);     \
      u32x4 pw;                                                          \
      pw[0] = hi ? r0 : a0; pw[1] = hi ? r1 : a1;                        \
      pw[2] = hi ? b0 : r0; pw[3] = hi ? b1 : r1;                        \
      bf16x8 paf = __builtin_bit_cast(bf16x8, pw);                       \
      bf16x8 v0f = *(const bf16x8*)&Vt[cur][q_l][(KS)*16 + hi * 8];      \
      bf16x8 v1f = *(const bf16x8*)&Vt[cur][32 + q_l][(KS)*16 + hi * 8]; \
      o0 = MFMA32(v0f, paf, o0);                                         \
      o1 = MFMA32(v1f, paf, o1);                                         \
    }
    PV_KS(0, st0, 0)
    PV_KS(1, st0, 8)
    PV_KS(2, st1, 0)
    PV_KS(3, st1, 8)
#undef PV_KS
    // ---- land next V tile (transpose-write into the other buffer) ----
#pragma unroll
    for (int e = 0; e < 8; ++e) {
      Vt[nxt][vds + e][vkey] = v0n[e];
      Vt[nxt][vds + 8 + e][vkey] = v1n[e];
    }
    __syncthreads();  // staged K (vmcnt) + Vt writes visible; cur reads done
  }
  // ---- epilogue: O[q][d], q = q_l lane-local; d = dt*32 + 8g + 4hi + j ----
  const float inv = 1.f / l_i;
  const size_t row = (size_t)(b * SL + qt * 128 + wq + q_l) * CD + h * HD;
#pragma unroll
  for (int g = 0; g < 4; ++g) {
    uint2 w0, w1;
    w0.x = pkbf(o0[4 * g + 0] * inv, o0[4 * g + 1] * inv);
    w0.y = pkbf(o0[4 * g + 2] * inv, o0[4 * g + 3] * inv);
    *(uint2*)&ctx[row + 8 * g + 4 * hi] = w0;
    w1.x = pkbf(o1[4 * g + 0] * inv, o1[4 * g + 1] * inv);
    w1.y = pkbf(o1[4 * g + 2] * inv, o1[4 * g + 3] * inv);
    *(uint2*)&ctx[row + 32 + 8 * g + 4 * hi] = w1;
  }
#undef STAGE_K
}

extern "C" void kernel_launch(void* const* d_in, const int* in_sizes, int n_in,
                              void* d_out, int out_size, void* d_ws, size_t ws_size,
                              hipStream_t stream) {
  const float* x     = (const float*)d_in[0];  // (8,32,32,768) fp32
  const float* w_qkv = (const float*)d_in[1];  // (2304,768) fp32
  const float* qg    = (const float*)d_in[2];  // (64,) fp32
  const float* kg    = (const float*)d_in[3];  // (64,) fp32
  const float* w_out = (const float*)d_in[4];  // (768,768) fp32
  // d_out: fp32.

  // ws: xb | wqb | wob | qkv | ctx (bf16) | rtab (float2, 256KB)
  unsigned short* xb  = (unsigned short*)d_ws;
  unsigned short* wqb = xb + (size_t)NB * SL * CD;
  unsigned short* wob = wqb + (size_t)QKVD * CD;
  unsigned short* qkv = wob + (size_t)CD * CD;
  unsigned short* ctx = qkv + (size_t)NB * SL * QKVD;
  float2* rtab = (float2*)(ctx + (size_t)NB * SL * CD);

  const int M = NB * SL;  // 8192
  dim3 blk(256);
  // 0) fused converts + RoPE table (one launch)
  prep_kernel<<<dim3((PN0 + PN1 + PN2 + PN3) / 256), blk, 0, stream>>>(
      (const float4*)x, (const float4*)w_qkv, (const float4*)w_out,
      (ushort4*)xb, (ushort4*)wqb, (ushort4*)wob, rtab);
  // 1) qkv = x @ w_qkv^T with fused RMSNorm+RoPE; 256x128 tile (WR=2),
  //    grid (18,32)=576 blocks (%8==0 for XCD swizzle)
  gemm_mfma<2, 2><<<dim3(QKVD / 128, M / 256), blk, 0, stream>>>(
      xb, wqb, qkv, M, QKVD, CD, qg, kg, rtab);
  // 2) attention -> ctx (bf16)
  attn_mfma<<<dim3(SL / 128, NHH, NB), blk, 0, stream>>>(qkv, ctx);
  // 3) out = ctx @ w_out^T (fp32 out); 128x128 tile (N=768 would
  //    under-occupy at 256 rows), grid (6,64)=384
  gemm_mfma<1, 1><<<dim3(CD / 128, M / 128), blk, 0, stream>>>(
      ctx, wob, d_out, M, CD, CD, nullptr, nullptr, nullptr);
}